// Round 3
// baseline (929.566 us; speedup 1.0000x reference)
//
#include <hip/hip_runtime.h>
#include <hip/hip_bf16.h>

#define B_TOK 2048
#define DIM 1024
#define INTER 2048
#define NEXP 8
#define LANG 768
#define SHARED_H 4096

typedef unsigned short u16;
typedef unsigned long long u64;
typedef __attribute__((ext_vector_type(8))) short bf16x8;
typedef __attribute__((ext_vector_type(4))) float f32x4;

__device__ __forceinline__ u16 f2bf(float f) {
    __hip_bfloat16 h = __float2bfloat16(f);      // native v_cvt, 1 VALU op
    return __builtin_bit_cast(u16, h);
}

__device__ __forceinline__ float silu_f(float x) { return x / (1.f + __expf(-x)); }

// ---------------- K1: routing (cos-sim argmax) + fused x->bf16 convert ----------------
// One wave per token. Each wave reads all of route_emb anyway, so per-expert norms
// are computed in-flight (no separate init kernel, no meta dependency).
__global__ void k_route(const float* __restrict__ lt, const float* __restrict__ re,
                        const float* __restrict__ x, u16* __restrict__ xb,
                        int* __restrict__ idx) {
    int wave = threadIdx.x >> 6, lane = threadIdx.x & 63;
    int tok = blockIdx.x * 4 + wave;
    const float* ltp = lt + (size_t)tok * LANG;
    float acc[NEXP], nrm[NEXP];
#pragma unroll
    for (int e = 0; e < NEXP; ++e) { acc[e] = 0.f; nrm[e] = 0.f; }
    for (int j = 0; j < LANG / 64; ++j) {
        float v = ltp[lane + j * 64];
#pragma unroll
        for (int e = 0; e < NEXP; ++e) {
            float w = re[e * LANG + lane + j * 64];
            acc[e] += v * w;
            nrm[e] += w * w;
        }
    }
#pragma unroll
    for (int e = 0; e < NEXP; ++e)
        for (int off = 32; off; off >>= 1) {
            acc[e] += __shfl_xor(acc[e], off);
            nrm[e] += __shfl_xor(nrm[e], off);
        }
    if (lane == 0) {
        float best = -1e30f; int bi = 0;
#pragma unroll
        for (int e = 0; e < NEXP; ++e) {
            float s = acc[e] / fmaxf(sqrtf(nrm[e]), 1e-12f);
            if (s > best) { best = s; bi = e; }     // strict > : first max wins (argmax tie rule)
        }
        idx[tok] = bi;
    }
    // ---- fused convert: x (f32) -> xb (bf16), 16 elements/thread ----
    size_t i = ((size_t)blockIdx.x * 256 + threadIdx.x) * 16;
#pragma unroll
    for (int h = 0; h < 2; ++h) {
        float4 a = *(const float4*)(x + i + h * 8);
        float4 b = *(const float4*)(x + i + h * 8 + 4);
        uint4 o;
        o.x = f2bf(a.x) | ((unsigned)f2bf(a.y) << 16);
        o.y = f2bf(a.z) | ((unsigned)f2bf(a.w) << 16);
        o.z = f2bf(b.x) | ((unsigned)f2bf(b.y) << 16);
        o.w = f2bf(b.z) | ((unsigned)f2bf(b.w) << 16);
        *(uint4*)(xb + i + h * 8) = o;
    }
}

// ---------------- K2: single-block histogram + prefix + cursor init + perm pad ----------------
// Robust to 0xAA ws poisoning: derives everything from idx[], assumes nothing pre-zeroed.
__global__ void k_scan(const int* __restrict__ idx, int* __restrict__ meta, int* __restrict__ perm) {
    __shared__ int cnt[NEXP];
    int tid = threadIdx.x;
    if (tid < NEXP) cnt[tid] = 0;
    __syncthreads();
    for (int i = tid; i < B_TOK; i += 256) atomicAdd(&cnt[idx[i]], 1);
    __syncthreads();
    if (tid == 0) {
        int off = 0;
        for (int e = 0; e < NEXP; ++e) {
            meta[e] = cnt[e];          // counts
            meta[8 + e] = 0;           // cursors
            meta[16 + e] = off;        // offsets
            off += cnt[e];
        }
    }
    if (tid >= 64 && tid < 64 + 128) perm[B_TOK + (tid - 64)] = 0;   // pad -> token 0
}

// ---------------- K3: scatter token ids into expert-grouped order ----------------
__global__ void k_scatter(const int* __restrict__ idx, int* __restrict__ meta, int* __restrict__ perm) {
    int b = blockIdx.x * blockDim.x + threadIdx.x;
    int e = idx[b];
    int pos = meta[16 + e] + atomicAdd(&meta[8 + e], 1);
    perm[pos] = b;
}

// ---------------- unified bf16-MFMA GEMM ----------------
// MODE 0: zh  = silu(xb @ Ws1 + bs1)                      [bf16 store]  BN=128
// MODE 1: out = zh @ Ws2 + bs2                            [f32 store]   BN=64
// MODE 2: h   = silu(xg@W1[e]+b1) * (xg@W3[e]+b3)         [gathered A]  BN=128
// MODE 3: out[perm[r]] += ew[e] * (h @ W2[e] + b2)        [scatter RMW] BN=64
template<int MODE, int BN>
__global__ void __launch_bounds__(256) k_gemm(
    const u16* __restrict__ A, const float* __restrict__ Bg, const float* __restrict__ Bg2,
    const float* __restrict__ bias, const float* __restrict__ bias2,
    const float* __restrict__ ew, u16* __restrict__ outB, float* __restrict__ outF,
    const int* __restrict__ perm, const int* __restrict__ meta)
{
    constexpr int BM = 128, BK = 32, BKP = 40;   // +8 pad: 80B rows, 16B-aligned chunks
    constexpr int K   = (MODE == 0) ? DIM : (MODE == 1) ? SHARED_H : (MODE == 2) ? DIM : INTER;
    constexpr int LDA = K;
    constexpr int LDB = (MODE == 0) ? SHARED_H : (MODE == 1) ? DIM : (MODE == 2) ? INTER : DIM;
    constexpr bool DUAL = (MODE == 2);
    constexpr bool EXP  = (MODE >= 2);
    // wave layout: BN=128 -> 2x2 waves (4x4 frags); BN=64 -> 4x1 waves (2x4 frags)
    constexpr int WN = (BN == 128) ? 2 : 1;
    constexpr int MF = (BN == 128) ? 4 : 2;
    constexpr int NF = 4;
    constexpr int WMR = MF * 16;     // rows per wave
    // B staging geometry: tasks = BN rows x 8 k-quads, 256 threads
    constexpr int KH  = 256 / BN;    // k-quad phases per pass
    constexpr int NJ  = 8 / KH;      // k-quad passes per thread
    constexpr int KHS = (BN == 128) ? 7 : 6;

    __shared__ u16 sA[BM * BKP];
    __shared__ u16 sB[BN * BKP];
    __shared__ u16 sB2[DUAL ? BN * BKP : 8];
    __shared__ int sPerm[EXP ? BM : 8];

    const int tid = threadIdx.x;
    const int m0 = blockIdx.x * BM;
    const int n0 = blockIdx.y * BN;
    int gstart = 0, Mg = B_TOK, e = 0;
    if (EXP) {
        e = blockIdx.z;
        gstart = meta[16 + e];
        Mg = meta[e];
        if (m0 >= Mg) return;            // uniform per block: safe early-exit
    }
    const float* Bp  = Bg + (EXP ? (size_t)e * K * LDB : (size_t)0);
    const float* B2p = DUAL ? (Bg2 + (size_t)e * K * LDB) : nullptr;

    if (EXP) {
        for (int i = tid; i < BM; i += 256) sPerm[i] = perm[gstart + m0 + i];  // padded, always valid
    }
    __syncthreads();

    const int wave = tid >> 6, lane = tid & 63;
    const int wr = wave / WN, wc = wave % WN;
    const int lr = lane & 15, lk8 = (lane >> 4) * 8;
    const int cR = lk8 >> 3;                 // 16B chunk index this lane reads

    // B staging thread mapping
    const int nnS = tid & (BN - 1);
    const int khS = tid >> KHS;
    const int swS = (nnS >> 3) & 3;          // XOR swizzle (breaks 80B-stride bank aliasing)

    f32x4 acc[MF][NF], acc3[DUAL ? MF : 1][DUAL ? NF : 1];
    f32x4 zero = {0.f, 0.f, 0.f, 0.f};
#pragma unroll
    for (int m = 0; m < MF; ++m)
#pragma unroll
        for (int n = 0; n < NF; ++n) acc[m][n] = zero;
    if constexpr (DUAL) {
#pragma unroll
        for (int m = 0; m < MF; ++m)
#pragma unroll
            for (int n = 0; n < NF; ++n) acc3[m][n] = zero;
    }

    for (int k0 = 0; k0 < K; k0 += BK) {
        // ---- stage A tile (bf16 [BM][BK], 16B vector copies) ----
#pragma unroll
        for (int i = 0; i < 2; ++i) {
            int vid = tid + i * 256;
            int r = vid >> 2, kb = vid & 3;
            size_t grow;
            if constexpr (MODE == 2) grow = (size_t)sPerm[r];
            else                     grow = (size_t)(gstart + m0 + r);
            const u16* src = A + grow * LDA + k0 + kb * 8;
            *(uint4*)&sA[r * BKP + kb * 8] = *(const uint4*)src;
        }
        // ---- stage B tile: f32 [K][N] -> bf16 [BN][BKP] transpose via packed b64 writes ----
        // thread (nnS, kq): 4 k-consecutive f32 (coalesced across lanes), packed to one u64,
        // chunk-swizzled write: chunk' = (kq>>1) ^ ((nn>>3)&3), half = kq&1
#pragma unroll
        for (int j = 0; j < NJ; ++j) {
            int kq = khS + KH * j;
            int boff = nnS * BKP + (((kq >> 1) ^ swS) << 3) + ((kq & 1) << 2);  // u16 units
            const float* src = Bp + (size_t)(k0 + kq * 4) * LDB + n0 + nnS;
            u64 v =  (u64)f2bf(src[0])
                  | ((u64)f2bf(src[(size_t)LDB])     << 16)
                  | ((u64)f2bf(src[(size_t)2 * LDB]) << 32)
                  | ((u64)f2bf(src[(size_t)3 * LDB]) << 48);
            *(u64*)&sB[boff] = v;
            if constexpr (DUAL) {
                const float* src2 = B2p + (size_t)(k0 + kq * 4) * LDB + n0 + nnS;
                u64 v2 =  (u64)f2bf(src2[0])
                       | ((u64)f2bf(src2[(size_t)LDB])     << 16)
                       | ((u64)f2bf(src2[(size_t)2 * LDB]) << 32)
                       | ((u64)f2bf(src2[(size_t)3 * LDB]) << 48);
                *(u64*)&sB2[boff] = v2;
            }
        }
        __syncthreads();

        bf16x8 aF[MF], bF[NF], b3F[NF];
#pragma unroll
        for (int m = 0; m < MF; ++m)
            aF[m] = *(const bf16x8*)&sA[(wr * WMR + m * 16 + lr) * BKP + lk8];
#pragma unroll
        for (int n = 0; n < NF; ++n) {
            int rowB = wc * 64 + n * 16 + lr;
            int co = ((cR ^ ((rowB >> 3) & 3)) << 3);
            bF[n] = *(const bf16x8*)&sB[rowB * BKP + co];
            if constexpr (DUAL) b3F[n] = *(const bf16x8*)&sB2[rowB * BKP + co];
        }
#pragma unroll
        for (int m = 0; m < MF; ++m)
#pragma unroll
            for (int n = 0; n < NF; ++n) {
                acc[m][n] = __builtin_amdgcn_mfma_f32_16x16x32_bf16(aF[m], bF[n], acc[m][n], 0, 0, 0);
                if constexpr (DUAL)
                    acc3[m][n] = __builtin_amdgcn_mfma_f32_16x16x32_bf16(aF[m], b3F[n], acc3[m][n], 0, 0, 0);
            }
        __syncthreads();
    }

    // ---- epilogue: row = wr*WMR + m*16 + (lane>>4)*4 + j, col = wc*64 + n*16 + (lane&15) ----
    const int lk4 = (lane >> 4) * 4;
    float wgt = (MODE == 3) ? ew[e] : 0.f;
#pragma unroll
    for (int m = 0; m < MF; ++m)
#pragma unroll
        for (int n = 0; n < NF; ++n)
#pragma unroll
            for (int j = 0; j < 4; ++j) {
                int row = wr * WMR + m * 16 + lk4 + j;
                int col = n0 + wc * 64 + n * 16 + lr;
                float v = acc[m][n][j];
                if constexpr (MODE == 0) {
                    v += bias[col];
                    outB[(size_t)(m0 + row) * SHARED_H + col] = f2bf(silu_f(v));
                } else if constexpr (MODE == 1) {
                    v += bias[col];
                    outF[(size_t)(m0 + row) * DIM + col] = v;
                } else if constexpr (MODE == 2) {
                    if (m0 + row < Mg) {
                        float v1 = v + bias[(size_t)e * INTER + col];
                        float v3 = acc3[m][n][j] + bias2[(size_t)e * INTER + col];
                        outB[(size_t)(gstart + m0 + row) * INTER + col] = f2bf(silu_f(v1) * v3);
                    }
                } else {
                    if (m0 + row < Mg) {
                        int tok = sPerm[row];
                        float* p = outF + (size_t)tok * DIM + col;
                        *p += wgt * (v + bias[(size_t)e * DIM + col]);
                    }
                }
            }
}

extern "C" void kernel_launch(void* const* d_in, const int* in_sizes, int n_in,
                              void* d_out, int out_size, void* d_ws, size_t ws_size,
                              hipStream_t stream) {
    const float* x   = (const float*)d_in[0];
    const float* lt  = (const float*)d_in[1];
    const float* re  = (const float*)d_in[2];
    const float* ew  = (const float*)d_in[3];
    const float* W1  = (const float*)d_in[4];
    const float* b1  = (const float*)d_in[5];
    const float* W2  = (const float*)d_in[6];
    const float* b2  = (const float*)d_in[7];
    const float* W3  = (const float*)d_in[8];
    const float* b3  = (const float*)d_in[9];
    const float* Ws1 = (const float*)d_in[10];
    const float* bs1 = (const float*)d_in[11];
    const float* Ws2 = (const float*)d_in[12];
    const float* bs2 = (const float*)d_in[13];
    float* out = (float*)d_out;

    char* ws = (char*)d_ws;
    int* meta = (int*)ws;                          // counts[8], cursors[8], offsets[8]
    int* idx  = (int*)(ws + 256);                  // 2048 ints
    int* perm = (int*)(ws + 256 + 8192);           // 2176 ints (128 pad)
    u16* xb   = (u16*)(ws + 32768);                // 2048x1024 bf16 = 4 MB
    u16* zh   = (u16*)(ws + 32768 + 4194304);      // 2048x4096 bf16 = 16 MB
    u16* h    = zh;                                 // reuse: zh dead before MODE-2 writes h

    k_route  <<<B_TOK / 4, 256, 0, stream>>>(lt, re, x, xb, idx);
    k_scan   <<<1, 256, 0, stream>>>(idx, meta, perm);
    k_scatter<<<B_TOK / 256, 256, 0, stream>>>(idx, meta, perm);

    k_gemm<0,128><<<dim3(16, SHARED_H / 128),    256, 0, stream>>>(xb, Ws1, nullptr, bs1, nullptr, nullptr, zh, nullptr, perm, meta);
    k_gemm<1, 64><<<dim3(16, DIM / 64),          256, 0, stream>>>(zh, Ws2, nullptr, bs2, nullptr, nullptr, nullptr, out, perm, meta);
    k_gemm<2,128><<<dim3(16, INTER / 128, NEXP), 256, 0, stream>>>(xb, W1, W3, b1, b3, nullptr, h, nullptr, perm, meta);
    k_gemm<3, 64><<<dim3(16, DIM / 64, NEXP),    256, 0, stream>>>(h, W2, nullptr, b2, nullptr, ew, nullptr, out, perm, meta);
}

// Round 6
// 723.102 us; speedup vs baseline: 1.2855x; 1.2855x over previous
//
#include <hip/hip_runtime.h>
#include <hip/hip_bf16.h>

#define B_TOK 2048
#define DIM 1024
#define INTER 2048
#define NEXP 8
#define LANG 768
#define SHARED_H 4096

typedef unsigned short u16;
typedef unsigned long long u64;
typedef __attribute__((ext_vector_type(8))) short bf16x8;
typedef __attribute__((ext_vector_type(4))) float f32x4;

__device__ __forceinline__ u16 f2bf(float f) {
    __hip_bfloat16 h = __float2bfloat16(f);      // native v_cvt
    return __builtin_bit_cast(u16, h);
}

__device__ __forceinline__ u64 pack4(const float* r) {
    return  (u64)f2bf(r[0])
         | ((u64)f2bf(r[1]) << 16)
         | ((u64)f2bf(r[2]) << 32)
         | ((u64)f2bf(r[3]) << 48);
}

__device__ __forceinline__ float silu_f(float x) { return x / (1.f + __expf(-x)); }

// ---------------- K1: routing (cos-sim argmax) + fused x->bf16 convert ----------------
__global__ void k_route(const float* __restrict__ lt, const float* __restrict__ re,
                        const float* __restrict__ x, u16* __restrict__ xb,
                        int* __restrict__ idx) {
    int wave = threadIdx.x >> 6, lane = threadIdx.x & 63;
    int tok = blockIdx.x * 4 + wave;
    const float* ltp = lt + (size_t)tok * LANG;
    float acc[NEXP], nrm[NEXP];
#pragma unroll
    for (int e = 0; e < NEXP; ++e) { acc[e] = 0.f; nrm[e] = 0.f; }
    for (int j = 0; j < LANG / 64; ++j) {
        float v = ltp[lane + j * 64];
#pragma unroll
        for (int e = 0; e < NEXP; ++e) {
            float w = re[e * LANG + lane + j * 64];
            acc[e] += v * w;
            nrm[e] += w * w;
        }
    }
#pragma unroll
    for (int e = 0; e < NEXP; ++e)
        for (int off = 32; off; off >>= 1) {
            acc[e] += __shfl_xor(acc[e], off);
            nrm[e] += __shfl_xor(nrm[e], off);
        }
    if (lane == 0) {
        float best = -1e30f; int bi = 0;
#pragma unroll
        for (int e = 0; e < NEXP; ++e) {
            float s = acc[e] / fmaxf(sqrtf(nrm[e]), 1e-12f);
            if (s > best) { best = s; bi = e; }     // strict > : first max wins (argmax tie rule)
        }
        idx[tok] = bi;
    }
    // ---- fused convert: x (f32) -> xb (bf16), 16 elements/thread ----
    size_t i = ((size_t)blockIdx.x * 256 + threadIdx.x) * 16;
#pragma unroll
    for (int h = 0; h < 2; ++h) {
        float4 a = *(const float4*)(x + i + h * 8);
        float4 b = *(const float4*)(x + i + h * 8 + 4);
        uint4 o;
        o.x = f2bf(a.x) | ((unsigned)f2bf(a.y) << 16);
        o.y = f2bf(a.z) | ((unsigned)f2bf(a.w) << 16);
        o.z = f2bf(b.x) | ((unsigned)f2bf(b.y) << 16);
        o.w = f2bf(b.z) | ((unsigned)f2bf(b.w) << 16);
        *(uint4*)(xb + i + h * 8) = o;
    }
}

// ---------------- K2: single-block histogram + prefix + cursor init + perm pad ----------------
__global__ void k_scan(const int* __restrict__ idx, int* __restrict__ meta, int* __restrict__ perm) {
    __shared__ int cnt[NEXP];
    int tid = threadIdx.x;
    if (tid < NEXP) cnt[tid] = 0;
    __syncthreads();
    for (int i = tid; i < B_TOK; i += 256) atomicAdd(&cnt[idx[i]], 1);
    __syncthreads();
    if (tid == 0) {
        int off = 0;
        for (int e = 0; e < NEXP; ++e) {
            meta[e] = cnt[e];          // counts
            meta[8 + e] = 0;           // cursors
            meta[16 + e] = off;        // offsets
            off += cnt[e];
        }
    }
    if (tid >= 64 && tid < 64 + 128) perm[B_TOK + (tid - 64)] = 0;   // pad -> token 0
}

// ---------------- K3: scatter token ids into expert-grouped order ----------------
__global__ void k_scatter(const int* __restrict__ idx, int* __restrict__ meta, int* __restrict__ perm) {
    int b = blockIdx.x * blockDim.x + threadIdx.x;
    int e = idx[b];
    int pos = meta[16 + e] + atomicAdd(&meta[8 + e], 1);
    perm[pos] = b;
}

// ---------------- unified bf16-MFMA GEMM, 2-phase reg-prefetch pipeline ----------------
// grid: blockIdx.x = n-tile (always active), blockIdx.y = m-tile, blockIdx.z = expert
// MODE 0: zh  = silu(xb @ Ws1 + bs1)                      [bf16 store]  BN=128
// MODE 1: out = zh @ Ws2 + bs2                            [f32 store]   BN=64
// MODE 2: h   = silu(xg@W1[e]+b1) * (xg@W3[e]+b3)         [gathered A]  BN=64
// MODE 3: out[perm[r]] += ew[e] * (h @ W2[e] + b2)        [scatter RMW] BN=64
template<int MODE, int BN>
__global__ void __launch_bounds__(256) k_gemm(
    const u16* __restrict__ A, const float* __restrict__ Bg, const float* __restrict__ Bg2,
    const float* __restrict__ bias, const float* __restrict__ bias2,
    const float* __restrict__ ew, u16* __restrict__ outB, float* __restrict__ outF,
    const int* __restrict__ perm, const int* __restrict__ meta)
{
    constexpr int BM = 128, BK = 32, BKP = 40;   // +8 pad: 80B rows, 16B-aligned chunks
    constexpr int K   = (MODE == 0) ? DIM : (MODE == 1) ? SHARED_H : (MODE == 2) ? DIM : INTER;
    constexpr int LDA = K;
    constexpr int LDB = (MODE == 0) ? SHARED_H : (MODE == 1) ? DIM : (MODE == 2) ? INTER : DIM;
    constexpr bool DUAL = (MODE == 2);
    constexpr bool EXP  = (MODE >= 2);
    constexpr int WN = (BN == 128) ? 2 : 1;
    constexpr int MF = (BN == 128) ? 4 : 2;
    constexpr int NF = 4;
    constexpr int WMR = MF * 16;
    constexpr int KH  = 256 / BN;    // k-quad phases per pass
    constexpr int NJ  = 8 / KH;      // k-quad passes per thread
    constexpr int KHS = (BN == 128) ? 7 : 6;

    __shared__ u16 sA[BM * BKP];
    __shared__ u16 sB[BN * BKP];
    __shared__ u16 sB2[DUAL ? BN * BKP : 8];
    __shared__ int sPerm[EXP ? BM : 8];

    const int tid = threadIdx.x;
    const int n0 = blockIdx.x * BN;
    const int m0 = blockIdx.y * BM;
    int gstart = 0, Mg = B_TOK, e = 0;
    if (EXP) {
        e = blockIdx.z;
        gstart = meta[16 + e];
        Mg = meta[e];
        if (m0 >= Mg) return;            // uniform per block: safe early-exit
    }
    const float* Bp  = Bg + (EXP ? (size_t)e * K * LDB : (size_t)0);
    const float* B2p = DUAL ? (Bg2 + (size_t)e * K * LDB) : nullptr;

    if (EXP) {
        for (int i = tid; i < BM; i += 256) sPerm[i] = perm[gstart + m0 + i];  // padded, always valid
    }
    __syncthreads();

    const int wave = tid >> 6, lane = tid & 63;
    const int wr = wave / WN, wc = wave % WN;
    const int lr = lane & 15, lk8 = (lane >> 4) * 8;
    const int cR = lk8 >> 3;                 // 16B chunk index this lane reads

    // ---- hoisted staging addresses ----
    const int nnS = tid & (BN - 1);
    const int khS = tid >> KHS;
    const int swS = (nnS >> 3) & 3;

    const u16* aSrc[2];
    int aDst[2];
#pragma unroll
    for (int i = 0; i < 2; ++i) {
        int vid = tid + i * 256;
        int r = vid >> 2, kb = vid & 3;
        size_t grow;
        if constexpr (MODE == 2) grow = (size_t)sPerm[r];
        else                     grow = (size_t)(gstart + m0 + r);
        aSrc[i] = A + grow * LDA + kb * 8;
        aDst[i] = r * BKP + kb * 8;
    }
    const float* bSrc[NJ];
    const float* b2Src[NJ];
    int bDst[NJ];
#pragma unroll
    for (int j = 0; j < NJ; ++j) {
        int kq = khS + KH * j;
        bSrc[j] = Bp + (size_t)(kq * 4) * LDB + n0 + nnS;
        if constexpr (DUAL) b2Src[j] = B2p + (size_t)(kq * 4) * LDB + n0 + nnS;
        bDst[j] = nnS * BKP + (((kq >> 1) ^ swS) << 3) + ((kq & 1) << 2);  // u16 units
    }

    uint4 rA[2];
    float rB[NJ][4];
    float rB2[DUAL ? NJ : 1][4];

    auto load_tile = [&](int k0) {
#pragma unroll
        for (int i = 0; i < 2; ++i) rA[i] = *(const uint4*)(aSrc[i] + k0);
#pragma unroll
        for (int j = 0; j < NJ; ++j) {
            const float* s = bSrc[j] + (size_t)k0 * LDB;
#pragma unroll
            for (int q = 0; q < 4; ++q) rB[j][q] = s[(size_t)q * LDB];
            if constexpr (DUAL) {
                const float* s2 = b2Src[j] + (size_t)k0 * LDB;
#pragma unroll
                for (int q = 0; q < 4; ++q) rB2[j][q] = s2[(size_t)q * LDB];
            }
        }
    };

    f32x4 acc[MF][NF], acc3[DUAL ? MF : 1][DUAL ? NF : 1];
    f32x4 zero = {0.f, 0.f, 0.f, 0.f};
#pragma unroll
    for (int m = 0; m < MF; ++m)
#pragma unroll
        for (int n = 0; n < NF; ++n) acc[m][n] = zero;
    if constexpr (DUAL) {
#pragma unroll
        for (int m = 0; m < MF; ++m)
#pragma unroll
            for (int n = 0; n < NF; ++n) acc3[m][n] = zero;
    }

    load_tile(0);    // prologue

    for (int k0 = 0; k0 < K; k0 += BK) {
        // ---- write phase: regs (tile k0) -> LDS; pack f32->bf16 here ----
#pragma unroll
        for (int i = 0; i < 2; ++i) *(uint4*)&sA[aDst[i]] = rA[i];
#pragma unroll
        for (int j = 0; j < NJ; ++j) {
            *(u64*)&sB[bDst[j]] = pack4(rB[j]);
            if constexpr (DUAL) *(u64*)&sB2[bDst[j]] = pack4(rB2[j]);
        }
        __syncthreads();
        // ---- issue next tile's global loads (latency hides under MFMA below) ----
        if (k0 + BK < K) load_tile(k0 + BK);
        // ---- compute phase ----
        bf16x8 aF[MF], bF[NF], b3F[NF];
#pragma unroll
        for (int m = 0; m < MF; ++m)
            aF[m] = *(const bf16x8*)&sA[(wr * WMR + m * 16 + lr) * BKP + lk8];
#pragma unroll
        for (int n = 0; n < NF; ++n) {
            int rowB = wc * 64 + n * 16 + lr;
            int co = ((cR ^ ((rowB >> 3) & 3)) << 3);
            bF[n] = *(const bf16x8*)&sB[rowB * BKP + co];
            if constexpr (DUAL) b3F[n] = *(const bf16x8*)&sB2[rowB * BKP + co];
        }
#pragma unroll
        for (int m = 0; m < MF; ++m)
#pragma unroll
            for (int n = 0; n < NF; ++n) {
                acc[m][n] = __builtin_amdgcn_mfma_f32_16x16x32_bf16(aF[m], bF[n], acc[m][n], 0, 0, 0);
                if constexpr (DUAL)
                    acc3[m][n] = __builtin_amdgcn_mfma_f32_16x16x32_bf16(aF[m], b3F[n], acc3[m][n], 0, 0, 0);
            }
        __syncthreads();
    }

    // ---- epilogue: row = wr*WMR + m*16 + (lane>>4)*4 + j, col = wc*64 + n*16 + (lane&15) ----
    const int lk4 = (lane >> 4) * 4;
    float wgt = (MODE == 3) ? ew[e] : 0.f;
#pragma unroll
    for (int m = 0; m < MF; ++m)
#pragma unroll
        for (int n = 0; n < NF; ++n)
#pragma unroll
            for (int j = 0; j < 4; ++j) {
                int row = wr * WMR + m * 16 + lk4 + j;
                int col = n0 + wc * 64 + n * 16 + lr;
                float v = acc[m][n][j];
                if constexpr (MODE == 0) {
                    v += bias[col];
                    outB[(size_t)(m0 + row) * SHARED_H + col] = f2bf(silu_f(v));
                } else if constexpr (MODE == 1) {
                    v += bias[col];
                    outF[(size_t)(m0 + row) * DIM + col] = v;
                } else if constexpr (MODE == 2) {
                    if (m0 + row < Mg) {
                        float v1 = v + bias[(size_t)e * INTER + col];
                        float v3 = acc3[m][n][j] + bias2[(size_t)e * INTER + col];
                        outB[(size_t)(gstart + m0 + row) * INTER + col] = f2bf(silu_f(v1) * v3);
                    }
                } else {
                    if (m0 + row < Mg) {
                        int tok = sPerm[row];
                        float* p = outF + (size_t)tok * DIM + col;
                        *p += wgt * (v + bias[(size_t)e * DIM + col]);
                    }
                }
            }
}

extern "C" void kernel_launch(void* const* d_in, const int* in_sizes, int n_in,
                              void* d_out, int out_size, void* d_ws, size_t ws_size,
                              hipStream_t stream) {
    const float* x   = (const float*)d_in[0];
    const float* lt  = (const float*)d_in[1];
    const float* re  = (const float*)d_in[2];
    const float* ew  = (const float*)d_in[3];
    const float* W1  = (const float*)d_in[4];
    const float* b1  = (const float*)d_in[5];
    const float* W2  = (const float*)d_in[6];
    const float* b2  = (const float*)d_in[7];
    const float* W3  = (const float*)d_in[8];
    const float* b3  = (const float*)d_in[9];
    const float* Ws1 = (const float*)d_in[10];
    const float* bs1 = (const float*)d_in[11];
    const float* Ws2 = (const float*)d_in[12];
    const float* bs2 = (const float*)d_in[13];
    float* out = (float*)d_out;

    char* ws = (char*)d_ws;
    int* meta = (int*)ws;                          // counts[8], cursors[8], offsets[8]
    int* idx  = (int*)(ws + 256);                  // 2048 ints
    int* perm = (int*)(ws + 256 + 8192);           // 2176 ints (128 pad)
    u16* xb   = (u16*)(ws + 32768);                // 2048x1024 bf16 = 4 MB
    u16* zh   = (u16*)(ws + 32768 + 4194304);      // 2048x4096 bf16 = 16 MB
    u16* h    = zh;                                 // reuse: zh dead before MODE-2 writes h

    k_route  <<<B_TOK / 4, 256, 0, stream>>>(lt, re, x, xb, idx);
    k_scan   <<<1, 256, 0, stream>>>(idx, meta, perm);
    k_scatter<<<B_TOK / 256, 256, 0, stream>>>(idx, meta, perm);

    // grid = (n-tiles, m-tiles, experts): x always active -> spreads across XCDs
    k_gemm<0,128><<<dim3(SHARED_H / 128, B_TOK / 128),       256, 0, stream>>>(xb, Ws1, nullptr, bs1, nullptr, nullptr, zh, nullptr, perm, meta);
    k_gemm<1, 64><<<dim3(DIM / 64,      B_TOK / 128),        256, 0, stream>>>(zh, Ws2, nullptr, bs2, nullptr, nullptr, nullptr, out, perm, meta);
    k_gemm<2, 64><<<dim3(INTER / 64,    B_TOK / 128, NEXP),  256, 0, stream>>>(xb, W1, W3, b1, b3, nullptr, h, nullptr, perm, meta);
    k_gemm<3, 64><<<dim3(DIM / 64,      B_TOK / 128, NEXP),  256, 0, stream>>>(h, W2, nullptr, b2, nullptr, ew, nullptr, out, perm, meta);
}

// Round 7
// 476.624 us; speedup vs baseline: 1.9503x; 1.5171x over previous
//
#include <hip/hip_runtime.h>
#include <hip/hip_bf16.h>

#define B_TOK 2048
#define DIM 1024
#define INTER 2048
#define NEXP 8
#define LANG 768
#define SHARED_H 4096

typedef unsigned short u16;
typedef unsigned long long u64;
typedef __attribute__((ext_vector_type(8))) short bf16x8;
typedef __attribute__((ext_vector_type(4))) float f32x4;

__device__ __forceinline__ u16 f2bf(float f) {
    __hip_bfloat16 h = __float2bfloat16(f);      // native v_cvt
    return __builtin_bit_cast(u16, h);
}

__device__ __forceinline__ u64 pack4(const float* r) {
    return  (u64)f2bf(r[0])
         | ((u64)f2bf(r[1]) << 16)
         | ((u64)f2bf(r[2]) << 32)
         | ((u64)f2bf(r[3]) << 48);
}

__device__ __forceinline__ float silu_f(float x) { return x / (1.f + __expf(-x)); }

// ---------------- K1: routing (cos-sim argmax) + fused x->bf16 convert ----------------
__global__ void k_route(const float* __restrict__ lt, const float* __restrict__ re,
                        const float* __restrict__ x, u16* __restrict__ xb,
                        int* __restrict__ idx) {
    int wave = threadIdx.x >> 6, lane = threadIdx.x & 63;
    int tok = blockIdx.x * 4 + wave;
    const float* ltp = lt + (size_t)tok * LANG;
    float acc[NEXP], nrm[NEXP];
#pragma unroll
    for (int e = 0; e < NEXP; ++e) { acc[e] = 0.f; nrm[e] = 0.f; }
    for (int j = 0; j < LANG / 64; ++j) {
        float v = ltp[lane + j * 64];
#pragma unroll
        for (int e = 0; e < NEXP; ++e) {
            float w = re[e * LANG + lane + j * 64];
            acc[e] += v * w;
            nrm[e] += w * w;
        }
    }
#pragma unroll
    for (int e = 0; e < NEXP; ++e)
        for (int off = 32; off; off >>= 1) {
            acc[e] += __shfl_xor(acc[e], off);
            nrm[e] += __shfl_xor(nrm[e], off);
        }
    if (lane == 0) {
        float best = -1e30f; int bi = 0;
#pragma unroll
        for (int e = 0; e < NEXP; ++e) {
            float s = acc[e] / fmaxf(sqrtf(nrm[e]), 1e-12f);
            if (s > best) { best = s; bi = e; }     // strict > : first max wins (argmax tie rule)
        }
        idx[tok] = bi;
    }
    // ---- fused convert: x (f32) -> xb (bf16), 16 elements/thread ----
    size_t i = ((size_t)blockIdx.x * 256 + threadIdx.x) * 16;
#pragma unroll
    for (int h = 0; h < 2; ++h) {
        float4 a = *(const float4*)(x + i + h * 8);
        float4 b = *(const float4*)(x + i + h * 8 + 4);
        uint4 o;
        o.x = f2bf(a.x) | ((unsigned)f2bf(a.y) << 16);
        o.y = f2bf(a.z) | ((unsigned)f2bf(a.w) << 16);
        o.z = f2bf(b.x) | ((unsigned)f2bf(b.y) << 16);
        o.w = f2bf(b.z) | ((unsigned)f2bf(b.w) << 16);
        *(uint4*)(xb + i + h * 8) = o;
    }
}

// ---------------- K2: single-block histogram + prefix + cursor init + perm pad ----------------
__global__ void k_scan(const int* __restrict__ idx, int* __restrict__ meta, int* __restrict__ perm) {
    __shared__ int cnt[NEXP];
    int tid = threadIdx.x;
    if (tid < NEXP) cnt[tid] = 0;
    __syncthreads();
    for (int i = tid; i < B_TOK; i += 256) atomicAdd(&cnt[idx[i]], 1);
    __syncthreads();
    if (tid == 0) {
        int off = 0;
        for (int e = 0; e < NEXP; ++e) {
            meta[e] = cnt[e];          // counts
            meta[8 + e] = 0;           // cursors
            meta[16 + e] = off;        // offsets
            off += cnt[e];
        }
    }
    if (tid >= 64 && tid < 64 + 128) perm[B_TOK + (tid - 64)] = 0;   // pad -> token 0
}

// ---------------- K3: scatter token ids into expert-grouped order ----------------
__global__ void k_scatter(const int* __restrict__ idx, int* __restrict__ meta, int* __restrict__ perm) {
    int b = blockIdx.x * blockDim.x + threadIdx.x;
    int e = idx[b];
    int pos = meta[16 + e] + atomicAdd(&meta[8 + e], 1);
    perm[pos] = b;
}

// ---------------- K4: out = bs2 + ew[idx[r]] * b2[idx[r]]  (bias pre-load for atomic accum) ----
__global__ void k_oinit(const int* __restrict__ idx, const float* __restrict__ ew,
                        const float* __restrict__ b2, const float* __restrict__ bs2,
                        float* __restrict__ out) {
    int r = blockIdx.x;
    int c = threadIdx.x * 4;
    int e = idx[r];
    float w = ew[e];
    float4 bb = *(const float4*)(bs2 + c);
    float4 bv = *(const float4*)(b2 + (size_t)e * DIM + c);
    float4 o;
    o.x = bb.x + w * bv.x; o.y = bb.y + w * bv.y;
    o.z = bb.z + w * bv.z; o.w = bb.w + w * bv.w;
    *(float4*)(out + (size_t)r * DIM + c) = o;
}

// ---------------- unified bf16-MFMA GEMM, 2-phase reg-prefetch, split-K capable ----------------
// grid: blockIdx.x = n-tile, blockIdx.y = m-tile, blockIdx.z = expert + NEXP*kslice (EXP) or kslice
// MODE 0: zh  = silu(xb @ Ws1 + bs1)                       [bf16 store]       BM=128 BN=128
// MODE 1: out += zh @ Ws2          (bias via k_oinit)      [f32 atomicAdd]    BM=64  BN=64 KS=2
// MODE 2: h   = silu(xg@W1[e]+b1) * (xg@W3[e]+b3)          [gathered A, bf16] BM=64  BN=64
// MODE 3: out[perm[r]] += ew[e]*(h @ W2[e]) (b2 in oinit)  [f32 atomicAdd]    BM=64  BN=64 KS=2
template<int MODE, int BM, int BN, int KSPLIT>
__global__ void __launch_bounds__(256) k_gemm(
    const u16* __restrict__ A, const float* __restrict__ Bg, const float* __restrict__ Bg2,
    const float* __restrict__ bias, const float* __restrict__ bias2,
    const float* __restrict__ ew, u16* __restrict__ outB, float* __restrict__ outF,
    const int* __restrict__ perm, const int* __restrict__ meta)
{
    constexpr int BK = 32, BKP = 40;   // +8 pad: 80B rows, 16B-aligned chunks
    constexpr int K   = (MODE == 0) ? DIM : (MODE == 1) ? SHARED_H : (MODE == 2) ? DIM : INTER;
    constexpr int Kc  = K / KSPLIT;
    constexpr int LDA = K;
    constexpr int LDB = (MODE == 0) ? SHARED_H : (MODE == 1) ? DIM : (MODE == 2) ? INTER : DIM;
    constexpr bool DUAL = (MODE == 2);
    constexpr bool EXP  = (MODE >= 2);
    // wave layout derived from tile: WN waves in n, WM in m; per-wave frag counts MF x NF
    constexpr int WN  = BN / 64;
    constexpr int WM  = 4 / WN;
    constexpr int MF  = BM / (WM * 16);
    constexpr int NF  = 4;
    constexpr int WMR = MF * 16;
    constexpr int AI  = BM / 64;     // A-staging uint4s per thread
    constexpr int KH  = 256 / BN;    // B-staging k-quad phases per pass
    constexpr int NJ  = 8 / KH;      // B-staging passes per thread
    constexpr int KHS = (BN == 128) ? 7 : 6;

    __shared__ u16 sA[BM * BKP];
    __shared__ u16 sB[BN * BKP];
    __shared__ u16 sB2[DUAL ? BN * BKP : 8];
    __shared__ int sPerm[EXP ? BM : 8];

    const int tid = threadIdx.x;
    const int n0 = blockIdx.x * BN;
    const int m0 = blockIdx.y * BM;
    int gstart = 0, Mg = B_TOK, e = 0, kslice = 0;
    if (EXP) { e = blockIdx.z & (NEXP - 1); kslice = blockIdx.z >> 3; }
    else     { kslice = blockIdx.z; }
    if (EXP) {
        gstart = meta[16 + e];
        Mg = meta[e];
        if (m0 >= Mg) return;            // uniform per block: safe early-exit
    }
    const int kbase = kslice * Kc;
    const float* Bp  = Bg + (EXP ? (size_t)e * K * LDB : (size_t)0);
    const float* B2p = DUAL ? (Bg2 + (size_t)e * K * LDB) : nullptr;

    if (EXP) {
        for (int i = tid; i < BM; i += 256) sPerm[i] = perm[gstart + m0 + i];  // padded, always valid
    }
    __syncthreads();

    const int wave = tid >> 6, lane = tid & 63;
    const int wr = wave / WN, wc = wave % WN;
    const int lr = lane & 15, lk8 = (lane >> 4) * 8;
    const int cR = lk8 >> 3;                 // 16B chunk index this lane reads

    // ---- hoisted staging addresses ----
    const int nnS = tid & (BN - 1);
    const int khS = tid >> KHS;
    const int swS = (nnS >> 3) & 3;

    const u16* aSrc[AI];
    int aDst[AI];
#pragma unroll
    for (int i = 0; i < AI; ++i) {
        int vid = tid + i * 256;
        int r = vid >> 2, kb = vid & 3;
        size_t grow;
        if constexpr (MODE == 2) grow = (size_t)sPerm[r];
        else                     grow = (size_t)(gstart + m0 + r);
        aSrc[i] = A + grow * LDA + kbase + kb * 8;
        aDst[i] = r * BKP + kb * 8;
    }
    const float* bSrc[NJ];
    const float* b2Src[NJ];
    int bDst[NJ];
#pragma unroll
    for (int j = 0; j < NJ; ++j) {
        int kq = khS + KH * j;
        bSrc[j] = Bp + (size_t)(kbase + kq * 4) * LDB + n0 + nnS;
        if constexpr (DUAL) b2Src[j] = B2p + (size_t)(kbase + kq * 4) * LDB + n0 + nnS;
        bDst[j] = nnS * BKP + (((kq >> 1) ^ swS) << 3) + ((kq & 1) << 2);  // u16 units
    }

    uint4 rA[AI];
    float rB[NJ][4];
    float rB2[DUAL ? NJ : 1][4];

    auto load_tile = [&](int k0) {
#pragma unroll
        for (int i = 0; i < AI; ++i) rA[i] = *(const uint4*)(aSrc[i] + k0);
#pragma unroll
        for (int j = 0; j < NJ; ++j) {
            const float* s = bSrc[j] + (size_t)k0 * LDB;
#pragma unroll
            for (int q = 0; q < 4; ++q) rB[j][q] = s[(size_t)q * LDB];
            if constexpr (DUAL) {
                const float* s2 = b2Src[j] + (size_t)k0 * LDB;
#pragma unroll
                for (int q = 0; q < 4; ++q) rB2[j][q] = s2[(size_t)q * LDB];
            }
        }
    };

    f32x4 acc[MF][NF], acc3[DUAL ? MF : 1][DUAL ? NF : 1];
    f32x4 zero = {0.f, 0.f, 0.f, 0.f};
#pragma unroll
    for (int m = 0; m < MF; ++m)
#pragma unroll
        for (int n = 0; n < NF; ++n) acc[m][n] = zero;
    if constexpr (DUAL) {
#pragma unroll
        for (int m = 0; m < MF; ++m)
#pragma unroll
            for (int n = 0; n < NF; ++n) acc3[m][n] = zero;
    }

    load_tile(0);    // prologue

    for (int k0 = 0; k0 < Kc; k0 += BK) {
        // ---- write phase: regs (tile k0) -> LDS; pack f32->bf16 here ----
#pragma unroll
        for (int i = 0; i < AI; ++i) *(uint4*)&sA[aDst[i]] = rA[i];
#pragma unroll
        for (int j = 0; j < NJ; ++j) {
            *(u64*)&sB[bDst[j]] = pack4(rB[j]);
            if constexpr (DUAL) *(u64*)&sB2[bDst[j]] = pack4(rB2[j]);
        }
        __syncthreads();
        // ---- issue next tile's global loads (latency hides under MFMA below) ----
        if (k0 + BK < Kc) load_tile(k0 + BK);
        // ---- compute phase ----
        bf16x8 aF[MF], bF[NF], b3F[NF];
#pragma unroll
        for (int m = 0; m < MF; ++m)
            aF[m] = *(const bf16x8*)&sA[(wr * WMR + m * 16 + lr) * BKP + lk8];
#pragma unroll
        for (int n = 0; n < NF; ++n) {
            int rowB = wc * 64 + n * 16 + lr;
            int co = ((cR ^ ((rowB >> 3) & 3)) << 3);
            bF[n] = *(const bf16x8*)&sB[rowB * BKP + co];
            if constexpr (DUAL) b3F[n] = *(const bf16x8*)&sB2[rowB * BKP + co];
        }
#pragma unroll
        for (int m = 0; m < MF; ++m)
#pragma unroll
            for (int n = 0; n < NF; ++n) {
                acc[m][n] = __builtin_amdgcn_mfma_f32_16x16x32_bf16(aF[m], bF[n], acc[m][n], 0, 0, 0);
                if constexpr (DUAL)
                    acc3[m][n] = __builtin_amdgcn_mfma_f32_16x16x32_bf16(aF[m], b3F[n], acc3[m][n], 0, 0, 0);
            }
        __syncthreads();
    }

    // ---- epilogue: row = wr*WMR + m*16 + (lane>>4)*4 + j, col = wc*64 + n*16 + (lane&15) ----
    const int lk4 = (lane >> 4) * 4;
    float wgt = (MODE == 3) ? ew[e] : 0.f;
#pragma unroll
    for (int m = 0; m < MF; ++m)
#pragma unroll
        for (int n = 0; n < NF; ++n)
#pragma unroll
            for (int j = 0; j < 4; ++j) {
                int row = wr * WMR + m * 16 + lk4 + j;
                int col = n0 + wc * 64 + n * 16 + lr;
                float v = acc[m][n][j];
                if constexpr (MODE == 0) {
                    v += bias[col];
                    outB[(size_t)(m0 + row) * SHARED_H + col] = f2bf(silu_f(v));
                } else if constexpr (MODE == 1) {
                    unsafeAtomicAdd(&outF[(size_t)(m0 + row) * DIM + col], v);
                } else if constexpr (MODE == 2) {
                    if (m0 + row < Mg) {
                        float v1 = v + bias[(size_t)e * INTER + col];
                        float v3 = acc3[m][n][j] + bias2[(size_t)e * INTER + col];
                        outB[(size_t)(gstart + m0 + row) * INTER + col] = f2bf(silu_f(v1) * v3);
                    }
                } else {
                    if (m0 + row < Mg) {
                        int tok = sPerm[row];
                        unsafeAtomicAdd(&outF[(size_t)tok * DIM + col], wgt * v);
                    }
                }
            }
}

extern "C" void kernel_launch(void* const* d_in, const int* in_sizes, int n_in,
                              void* d_out, int out_size, void* d_ws, size_t ws_size,
                              hipStream_t stream) {
    const float* x   = (const float*)d_in[0];
    const float* lt  = (const float*)d_in[1];
    const float* re  = (const float*)d_in[2];
    const float* ew  = (const float*)d_in[3];
    const float* W1  = (const float*)d_in[4];
    const float* b1  = (const float*)d_in[5];
    const float* W2  = (const float*)d_in[6];
    const float* b2  = (const float*)d_in[7];
    const float* W3  = (const float*)d_in[8];
    const float* b3  = (const float*)d_in[9];
    const float* Ws1 = (const float*)d_in[10];
    const float* bs1 = (const float*)d_in[11];
    const float* Ws2 = (const float*)d_in[12];
    const float* bs2 = (const float*)d_in[13];
    float* out = (float*)d_out;

    char* ws = (char*)d_ws;
    int* meta = (int*)ws;                          // counts[8], cursors[8], offsets[8]
    int* idx  = (int*)(ws + 256);                  // 2048 ints
    int* perm = (int*)(ws + 256 + 8192);           // 2176 ints (128 pad)
    u16* xb   = (u16*)(ws + 32768);                // 2048x1024 bf16 = 4 MB
    u16* zh   = (u16*)(ws + 32768 + 4194304);      // 2048x4096 bf16 = 16 MB
    u16* h    = zh;                                 // reuse: zh dead before MODE-2 writes h

    k_route  <<<B_TOK / 4, 256, 0, stream>>>(lt, re, x, xb, idx);
    k_scan   <<<1, 256, 0, stream>>>(idx, meta, perm);
    k_scatter<<<B_TOK / 256, 256, 0, stream>>>(idx, meta, perm);
    k_oinit  <<<B_TOK, 256, 0, stream>>>(idx, ew, b2, bs2, out);

    // grids: (n-tiles, m-tiles, expert + 8*kslice). 64^2 tiles + split-K -> ~1024 active blocks (4/CU)
    k_gemm<0,128,128,1><<<dim3(SHARED_H / 128, B_TOK / 128, 1), 256, 0, stream>>>(xb, Ws1, nullptr, bs1, nullptr, nullptr, zh, nullptr, perm, meta);
    k_gemm<1, 64, 64,2><<<dim3(DIM / 64,      B_TOK / 64, 2),   256, 0, stream>>>(zh, Ws2, nullptr, nullptr, nullptr, nullptr, nullptr, out, perm, meta);
    k_gemm<2, 64, 64,1><<<dim3(INTER / 64,    B_TOK / 64, NEXP),256, 0, stream>>>(xb, W1, W3, b1, b3, nullptr, h, nullptr, perm, meta);
    k_gemm<3, 64, 64,2><<<dim3(DIM / 64,      B_TOK / 64, NEXP * 2), 256, 0, stream>>>(h, W2, nullptr, nullptr, nullptr, ew, nullptr, out, perm, meta);
}